// Round 1
// baseline (108.361 us; speedup 1.0000x reference)
//
#include <hip/hip_runtime.h>
#include <math.h>

// ModifiedBarlowTwinsLoss — augmented-Gram formulation, bf16 MFMA.
// Y = [X | M] (M = one-hot labels, 128 padded classes). One MFMA pass gives:
//   X^T X  (10 upper 128x128 tiles)  -> Gram for term1 + column sumsq
//   X^T M  (4 tiles)                 -> per-class column sums R (term2, mu)
// loss = (1/D^2) sum Ga~ Gb~ - (2/D) sum_c Sa~·Sb~ + sum_c n_c^2
//
// R1 changes vs 118.3 µs baseline:
//  - k_gram: double-buffered LDS pipeline (1 barrier/K-step instead of 2;
//    next-step global_load_lds issued before compute of current step).
//  - k_gram: XCD-aware block swizzle — all 14 tiles of one (mat,chunk)
//    land on the same XCD so their shared 640 KB panel slice is L2-resident.
//  - k_init fused into k_convT (one launch fewer).
//  - k_gsum folded with float4 loads/stores (448 blocks).

#define NN 8192
#define DD 512
#define NC 100
#define SPLITK 16
#define NXT 10            // X^T X upper-triangle tiles
#define NTILE 14          // + 4 X^T M tiles

// ws byte offsets
#define GA_B    0u           // 512*512*4
#define GB_B    1048576u
#define RTA_B   2097152u     // RT: [128 classes][512 cols] f32 = 262144 B
#define RTB_B   2359296u
#define MUA_B   2621440u
#define MUB_B   2623488u
#define RSA_B   2625536u
#define RSB_B   2627584u
#define CNT_B   2629632u
#define XTA_B   4194304u     // 512*8192*2
#define XTB_B   12582912u
#define MT_B    20971520u    // 128*8192*2
#define PART_B  23068672u    // 2*14*16*16384*4 = 29,360,128 (end ~52.4 MB)

typedef __attribute__((ext_vector_type(8))) short short8;
typedef __attribute__((ext_vector_type(4))) float f32x4;

__constant__ int c_ti[NTILE] = {0,0,0,0,1,1,1,2,2,3, 0,1,2,3};
__constant__ int c_tj[NTILE] = {0,1,2,3,1,2,3,2,3,3, 4,4,4,4};
__constant__ float c_w[NXT]  = {1.f,2.f,2.f,2.f,1.f,2.f,2.f,1.f,2.f,1.f};

#if defined(__has_builtin)
#if __has_builtin(__builtin_amdgcn_global_load_lds)
#define HAVE_GLL 1
#endif
#endif

#ifdef HAVE_GLL
__device__ __forceinline__ void async16(const void* g, void* l) {
    __builtin_amdgcn_global_load_lds(
        (const __attribute__((address_space(1))) void*)g,
        (__attribute__((address_space(3))) void*)l, 16, 0, 0);
}
#endif

__device__ __forceinline__ short f2bf_rne(float f) {
    unsigned int u = __builtin_bit_cast(unsigned int, f);
    u += 0x7fffu + ((u >> 16) & 1u);
    return (short)(u >> 16);
}

__device__ __forceinline__ float block_reduce_sum(float v) {
    __shared__ float red[8];
    int lane = threadIdx.x & 63;
    int wave = threadIdx.x >> 6;
    #pragma unroll
    for (int off = 32; off > 0; off >>= 1) v += __shfl_down(v, off, 64);
    if (lane == 0) red[wave] = v;
    __syncthreads();
    float s = 0.f;
    if (threadIdx.x == 0) {
        int nw = (blockDim.x + 63) >> 6;
        for (int w = 0; w < nw; w++) s += red[w];
    }
    return s; // thread 0 only
}

// K1 (fused): blocks 0..2047 do fp32->bf16 transpose-convert;
// blocks 2048..2175 build one-hot MT[128][8192]; block 2176 zeroes out[0].
__global__ __launch_bounds__(256) void k_prep(const float* __restrict__ A,
                                              const float* __restrict__ B,
                                              const int* __restrict__ labels,
                                              short* __restrict__ XTa,
                                              short* __restrict__ XTb,
                                              short* __restrict__ MT,
                                              float* __restrict__ out) {
    __shared__ short LT[64][72];
    int bid = blockIdx.x;
    int t = threadIdx.x;

    if (bid >= 2048) {
        int c = bid - 2048;
        if (c == 128) { if (t == 0) out[0] = 0.f; return; }
        unsigned short one = 0x3F80; // bf16 1.0
        ushort4* dst = (ushort4*)(MT + (size_t)c * NN);
        const int4* lb4 = (const int4*)labels;
        #pragma unroll
        for (int j = 0; j < 8; j++) {
            int i4 = j * 256 + t;
            int4 lb = lb4[i4];
            ushort4 v;
            v.x = (lb.x == c) ? one : (unsigned short)0;
            v.y = (lb.y == c) ? one : (unsigned short)0;
            v.z = (lb.z == c) ? one : (unsigned short)0;
            v.w = (lb.w == c) ? one : (unsigned short)0;
            dst[i4] = v;
        }
        return;
    }

    const float* X = (bid >> 10) ? B : A;
    short* XT = (bid >> 10) ? XTb : XTa;
    int rem = bid & 1023;
    int c0 = (rem >> 7) << 6;
    int k0 = (rem & 127) << 6;

    int cc = t & 15;
    int kb = t >> 4;
    #pragma unroll
    for (int s = 0; s < 4; s++) {
        int kr = kb + s * 16;
        float4 v = *(const float4*)&X[(size_t)(k0 + kr) * DD + c0 + cc * 4];
        LT[cc * 4 + 0][kr] = f2bf_rne(v.x);
        LT[cc * 4 + 1][kr] = f2bf_rne(v.y);
        LT[cc * 4 + 2][kr] = f2bf_rne(v.z);
        LT[cc * 4 + 3][kr] = f2bf_rne(v.w);
    }
    __syncthreads();
    #pragma unroll
    for (int s = 0; s < 2; s++) {
        int idx = s * 256 + t;
        int orow = idx >> 3;
        int och = idx & 7;
        *(uint4*)&XT[(size_t)(c0 + orow) * NN + k0 + och * 8] =
            *(const uint4*)&LT[orow][och * 8];
    }
}

// K2: bf16 MFMA augmented Gram. 448 blocks = 2 mats x 14 tiles x 16 K-chunks.
// Double-buffered LDS (2x32 KB); XOR-swizzled chunks (c' = c ^ (row&7)).
// XCD swizzle: blockIdx % 8 selects the (mat,chunk) group's XCD so all 14
// tiles of a group share one XCD's L2 (distinct data/group = 640 KB).
__global__ __launch_bounds__(256, 2) void k_gram(const short* __restrict__ XTa,
                                                 const short* __restrict__ XTb,
                                                 const short* __restrict__ MT,
                                                 float* __restrict__ part) {
    __shared__ short LA[2][128 * 64];
    __shared__ short LB[2][128 * 64];

    int b = blockIdx.x;              // 0..447
    int xcd = b & 7;
    int idx = b >> 3;                // 0..55
    int grp = (idx / NTILE) * 8 + xcd;   // 0..31  (mat,chunk) group
    int tile = idx % NTILE;
    int mat = grp >> 4;
    int chunk = grp & 15;

    const short* XT = mat ? XTb : XTa;
    int ti = c_ti[tile], tj = c_tj[tile];
    const short* PA = XT + (size_t)ti * 128 * NN;
    const short* PB = (tj < 4) ? (XT + (size_t)tj * 128 * NN) : MT;
    int k0 = chunk * (NN / SPLITK);

    int t = threadIdx.x;
    int wave = t >> 6, lane = t & 63;
    int quad = lane >> 4, l16 = lane & 15;
    int x7 = l16 & 7;
    int wrow = (wave >> 1) * 64, wcol = (wave & 1) * 64;

    int srow = lane >> 3;                 // row within 8-row segment
    int sc = (lane & 7) ^ srow;           // swizzled global 16B-chunk index

    auto stage = [&](int buf, int kk) {
        #pragma unroll
        for (int rr = 0; rr < 4; rr++) {
            int seg = wave * 4 + rr;
            int row = seg * 8 + srow;
            const short* ga = PA + (size_t)row * NN + k0 + kk + sc * 8;
            const short* gb = PB + (size_t)row * NN + k0 + kk + sc * 8;
#ifdef HAVE_GLL
            async16(ga, &LA[buf][seg * 512]);
            async16(gb, &LB[buf][seg * 512]);
#else
            *(uint4*)&LA[buf][seg * 512 + lane * 8] = *(const uint4*)ga;
            *(uint4*)&LB[buf][seg * 512 + lane * 8] = *(const uint4*)gb;
#endif
        }
    };

    f32x4 acc[4][4];
    #pragma unroll
    for (int i = 0; i < 4; i++)
        #pragma unroll
        for (int j = 0; j < 4; j++) acc[i][j] = (f32x4)0.f;

    const int KR = NN / SPLITK;           // 512
    int cur = 0;
    stage(0, 0);
    __syncthreads();                      // drains vmcnt(0): buf0 ready

    for (int kk = 0; kk < KR; kk += 64) {
        if (kk + 64 < KR) stage(cur ^ 1, kk + 64);  // prefetch next step
        #pragma unroll
        for (int ks = 0; ks < 2; ks++) {
            short8 a[4], bfr[4];
            #pragma unroll
            for (int mt = 0; mt < 4; mt++)
                a[mt] = *(const short8*)&LA[cur][(wrow + mt * 16 + l16) * 64 +
                                                 (((ks * 4 + quad) ^ x7) << 3)];
            #pragma unroll
            for (int nt = 0; nt < 4; nt++)
                bfr[nt] = *(const short8*)&LB[cur][(wcol + nt * 16 + l16) * 64 +
                                                   (((ks * 4 + quad) ^ x7) << 3)];
            #pragma unroll
            for (int mt = 0; mt < 4; mt++)
                #pragma unroll
                for (int nt = 0; nt < 4; nt++)
                    acc[mt][nt] = __builtin_amdgcn_mfma_f32_16x16x32_bf16(
                        a[mt], bfr[nt], acc[mt][nt], 0, 0, 0);
        }
        __syncthreads();   // drains vmcnt(0): next buffer staged; cur reads done
        cur ^= 1;
    }

    float* pbase = part + ((size_t)(mat * NTILE + tile) * SPLITK + chunk) * 16384;
    #pragma unroll
    for (int mt = 0; mt < 4; mt++)
        #pragma unroll
        for (int nt = 0; nt < 4; nt++)
            #pragma unroll
            for (int rj = 0; rj < 4; rj++) {
                int rr2 = wrow + mt * 16 + quad * 4 + rj;
                int cc2 = wcol + nt * 16 + l16;
                pbase[rr2 * 128 + cc2] = acc[mt][nt][rj];
            }
}

// K3: fold SPLITK partials -> Ga/Gb (XX tiles) and RT[class][col] (XM tiles).
// float4 loads: 448 blocks, each folds 1024 elements over 16 chunks.
__global__ void k_gsum(const float* __restrict__ part,
                       float* __restrict__ Ga, float* __restrict__ Gb,
                       float* __restrict__ RTa, float* __restrict__ RTb) {
    int bid = blockIdx.x;                  // 2*14*16 = 448
    int mat = bid / (NTILE * 16);
    int rr = bid % (NTILE * 16);
    int tile = rr / 16;
    int e4 = (rr % 16) * 1024 + threadIdx.x * 4;
    const float4* p = (const float4*)(part +
        (size_t)(mat * NTILE + tile) * SPLITK * 16384 + e4);
    float4 s = make_float4(0.f, 0.f, 0.f, 0.f);
    #pragma unroll
    for (int c = 0; c < SPLITK; c++) {
        float4 v = p[(size_t)c * 4096];
        s.x += v.x; s.y += v.y; s.z += v.z; s.w += v.w;
    }
    int rw = e4 >> 7, cl = e4 & 127;
    if (tile < NXT) {
        float* G = mat ? Gb : Ga;
        *(float4*)&G[(c_ti[tile] * 128 + rw) * DD + c_tj[tile] * 128 + cl] = s;
    } else {
        float* RT = mat ? RTb : RTa;
        int col = (tile - NXT) * 128 + rw;     // [class][col]
        RT[(size_t)(cl + 0) * DD + col] = s.x;
        RT[(size_t)(cl + 1) * DD + col] = s.y;
        RT[(size_t)(cl + 2) * DD + col] = s.z;
        RT[(size_t)(cl + 3) * DD + col] = s.w;
    }
}

// K4: column stats (mu from class sums, sumsq from Gram diag) + label histogram.
__global__ void k_stats(const float* __restrict__ Ga, const float* __restrict__ Gb,
                        const float* __restrict__ RTa, const float* __restrict__ RTb,
                        const int* __restrict__ labels,
                        float* mu_a, float* mu_b, float* rs_a, float* rs_b,
                        int* counts) {
    if (blockIdx.x == 2) {
        __shared__ int h[NC];
        int t = threadIdx.x;
        if (t < NC) h[t] = 0;
        __syncthreads();
        for (int i = t; i < NN; i += blockDim.x) atomicAdd(&h[labels[i]], 1);
        __syncthreads();
        if (t < NC) counts[t] = h[t];
        return;
    }
    int mat = blockIdx.x;
    int k = threadIdx.x;
    const float* RT = mat ? RTb : RTa;
    const float* G = mat ? Gb : Ga;
    float s = 0.f;
    for (int c = 0; c < 128; c++) s += RT[c * DD + k];
    float mu = s / (float)NN;
    float sumsq = G[k * DD + k];
    float var = (sumsq - (float)NN * mu * mu) / (float)(NN - 1);
    (mat ? mu_b : mu_a)[k] = mu;
    (mat ? rs_b : rs_a)[k] = rsqrtf(var);
}

// K5: blocks 0..255: term1 over stored tiles (diag w=1, off-diag w=2);
//     blocks 256..355: term2 per class; block 256 also adds term3.
__global__ void k_term(const float* __restrict__ Ga, const float* __restrict__ Gb,
                       const float* __restrict__ RTa, const float* __restrict__ RTb,
                       const float* __restrict__ mu_a, const float* __restrict__ mu_b,
                       const float* __restrict__ rs_a, const float* __restrict__ rs_b,
                       const int* __restrict__ counts, float* out) {
    int bid = blockIdx.x;
    if (bid < 256) {
        float local = 0.f;
        for (int x = bid * 256 + threadIdx.x; x < NXT * 16384; x += 256 * 256) {
            int tile = x >> 14, e = x & 16383;
            int gi = c_ti[tile] * 128 + (e >> 7);
            int gj = c_tj[tile] * 128 + (e & 127);
            float ga = rs_a[gi] * rs_a[gj] * (Ga[gi * DD + gj] - (float)NN * mu_a[gi] * mu_a[gj]);
            float gb = rs_b[gi] * rs_b[gj] * (Gb[gi * DD + gj] - (float)NN * mu_b[gi] * mu_b[gj]);
            local += c_w[tile] * ga * gb;
        }
        float s = block_reduce_sum(local);
        if (threadIdx.x == 0) atomicAdd(out, s * (1.0f / ((float)DD * (float)DD)));
    } else {
        int c = bid - 256;
        float n = (float)counts[c];
        float local = 0.f;
        for (int k = threadIdx.x; k < DD; k += 256) {
            float ta = rs_a[k] * (RTa[c * DD + k] - n * mu_a[k]);
            float tb = rs_b[k] * (RTb[c * DD + k] - n * mu_b[k]);
            local += ta * tb;
        }
        float s = block_reduce_sum(local);
        if (threadIdx.x == 0) {
            float add = s * (-2.0f / (float)DD);
            if (c == 0) {
                float t3 = 0.f;
                for (int cc = 0; cc < NC; cc++) {
                    float nc = (float)counts[cc];
                    t3 += nc * nc;
                }
                add += t3;
            }
            atomicAdd(out, add);
        }
    }
}

extern "C" void kernel_launch(void* const* d_in, const int* in_sizes, int n_in,
                              void* d_out, int out_size, void* d_ws, size_t ws_size,
                              hipStream_t stream) {
    const float* z_a = (const float*)d_in[0];
    const float* z_b = (const float*)d_in[1];
    const int* labels = (const int*)d_in[2];
    float* out = (float*)d_out;
    char* wsb = (char*)d_ws;

    float* Ga = (float*)(wsb + GA_B);
    float* Gb = (float*)(wsb + GB_B);
    float* RTa = (float*)(wsb + RTA_B);
    float* RTb = (float*)(wsb + RTB_B);
    float* mu_a = (float*)(wsb + MUA_B);
    float* mu_b = (float*)(wsb + MUB_B);
    float* rs_a = (float*)(wsb + RSA_B);
    float* rs_b = (float*)(wsb + RSB_B);
    int* counts = (int*)(wsb + CNT_B);
    short* XTa = (short*)(wsb + XTA_B);
    short* XTb = (short*)(wsb + XTB_B);
    short* MT = (short*)(wsb + MT_B);
    float* part = (float*)(wsb + PART_B);

    hipLaunchKernelGGL(k_prep, dim3(2177), dim3(256), 0, stream,
                       z_a, z_b, labels, XTa, XTb, MT, out);
    hipLaunchKernelGGL(k_gram, dim3(2 * NTILE * SPLITK), dim3(256), 0, stream,
                       XTa, XTb, MT, part);
    hipLaunchKernelGGL(k_gsum, dim3(2 * NTILE * 16), dim3(256), 0, stream,
                       part, Ga, Gb, RTa, RTb);
    hipLaunchKernelGGL(k_stats, dim3(3), dim3(512), 0, stream,
                       Ga, Gb, RTa, RTb, labels, mu_a, mu_b, rs_a, rs_b, counts);
    hipLaunchKernelGGL(k_term, dim3(356), dim3(256), 0, stream,
                       Ga, Gb, RTa, RTb, mu_a, mu_b, rs_a, rs_b, counts, out);
}